// Round 1
// baseline (175.707 us; speedup 1.0000x reference)
//
#include <hip/hip_runtime.h>
#include <hip/hip_bf16.h>

#define N_NODES_C 20000
#define N_EDGES_C 200000

#define PW0_C       0.17677669529663687f   // sqrt(1/32)
#define PW1_C       0.30618621784789724f   // sqrt(3/32)
#define INV_SQRT3_C 0.57735026918962576f
#define SI_NORM_C   0.25f                  // 1/sqrt(16)

typedef __attribute__((ext_vector_type(8))) short short8;
typedef __attribute__((ext_vector_type(4))) float f32x4;

__device__ __forceinline__ unsigned short f2bf(float x) {
    union { float f; unsigned u; } v; v.f = x;
    unsigned r = v.u + 0x7fffu + ((v.u >> 16) & 1u);   // RNE
    return (unsigned short)(r >> 16);
}

// ---------------- K0: h = silu(edge_attr @ w1 + b1), bf16 ----------------
__global__ __launch_bounds__(256) void k_h(const float* __restrict__ ea,
                                           const float* __restrict__ w1,
                                           const float* __restrict__ b1,
                                           unsigned short* __restrict__ h) {
    int idx = blockIdx.x * 256 + threadIdx.x;        // E*64 = 12.8M exact
    int e = idx >> 6, c = idx & 63;
    const float* a = ea + e * 8;                     // broadcast within wave
    float acc = b1[c];
    #pragma unroll
    for (int k = 0; k < 8; ++k) acc = fmaf(a[k], w1[k * 64 + c], acc);
    float s = acc / (1.0f + __expf(-acc));
    h[idx] = f2bf(s);
}

// ---------------- K0b: repack w2 -> bf16 B-fragment layout ----------------
// dest[tid]: tid = ((u*4+k)*2+ks)*512 + l*8 + j
// value = w2[ ks*32 + (l>>4)*8 + j ][ k*256 + u*16 + (l&15) ]
__global__ __launch_bounds__(256) void k_w2(const float* __restrict__ w2,
                                            unsigned short* __restrict__ w2f) {
    int tid = blockIdx.x * 256 + threadIdx.x;        // 65536 exact
    int j  = tid & 7;
    int l  = (tid >> 3) & 63;
    int ks = (tid >> 9) & 1;
    int tp = tid >> 10;                              // u*4+k
    int u = tp >> 2, k = tp & 3;
    int krow = ks * 32 + (l >> 4) * 8 + j;
    int col  = k * 256 + u * 16 + (l & 15);
    w2f[tid] = f2bf(w2[krow * 1024 + col]);
}

// ---------------- K_si: self-interaction, writes (initializes) d_out ------
__global__ __launch_bounds__(256) void k_si(const float* __restrict__ nf,
                                            const float* __restrict__ wsi0,
                                            const float* __restrict__ wsi1,
                                            float* __restrict__ out) {
    int idx = blockIdx.x * 256 + threadIdx.x;        // 20000*64 = 1.28M exact
    int n = idx >> 6, c = idx & 63;
    const float* x = nf + n * 64;
    float acc = 0.f;
    if (c < 16) {
        #pragma unroll
        for (int u = 0; u < 16; ++u) acc = fmaf(x[u], wsi0[u * 16 + c], acc);
    } else {
        int w = (c - 16) / 3, m = (c - 16) - w * 3;
        #pragma unroll
        for (int u = 0; u < 16; ++u) acc = fmaf(x[16 + u * 3 + m], wsi1[u * 16 + w], acc);
    }
    out[idx] = acc * SI_NORM_C;
}

// ---------------- K_main: fused h@w2 (MFMA) + contraction + scatter -------
// Block: 256 thr = 4 waves, 64 edges. Wave w: edges [64*blk + 16w, +16).
// Per (k,u) col-tile: C[e][w] = (h @ w2)[e][k*256+u*16+w] via 2x mfma 16x16x32.
// Message accumulation in-register using per-edge scalars from LDS.
__global__ __launch_bounds__(256) void k_main(const float* __restrict__ nf,
                                              const float* __restrict__ sh,
                                              const int* __restrict__ ei,
                                              const unsigned short* __restrict__ h,
                                              const unsigned short* __restrict__ w2f,
                                              const float* __restrict__ b2,
                                              float* __restrict__ out) {
    __shared__ unsigned short w2s[2][4096];   // 16 KB dbuf; aliased as nf_s in phase A
    __shared__ float S[6][16][64];            // 24 KB: [class][u][edge_local]
    __shared__ float sh_s[64][4];             // 1 KB
    __shared__ float b2_s[4][16][16];         // 4 KB
    __shared__ int   row_s[64];

    float (*nf_s)[64] = (float (*)[64])w2s;   // phase-A alias (dead before w2s use)

    const int t    = threadIdx.x;
    const int e0   = blockIdx.x * 64;
    const int lane = t & 63;
    const int wid  = t >> 6;

    // ---- phase A: gather node rows / sh / row / b2 ----
    {
        float* b2flat = &b2_s[0][0][0];
        #pragma unroll
        for (int i = 0; i < 4; ++i) b2flat[t + i * 256] = b2[t + i * 256];
        int el = t >> 2, part = t & 3;
        int col = ei[N_EDGES_C + e0 + el];
        const f32x4* src = (const f32x4*)(nf + col * 64);
        #pragma unroll
        for (int q = 0; q < 4; ++q)
            *(f32x4*)&nf_s[el][part * 16 + q * 4] = src[part * 4 + q];
        if (part == 0) {
            *(f32x4*)&sh_s[el][0] = *(const f32x4*)(sh + (e0 + el) * 4);
            row_s[el] = ei[e0 + el];
        }
    }
    // A-fragments from h (global, L2-warm): lane holds row=lane&15, k=(lane>>4)*8+j
    const unsigned short* hrow = h + (e0 + wid * 16 + (lane & 15)) * 64 + ((lane >> 4) * 8);
    short8 a0 = *(const short8*)(hrow);        // k in [0,32)
    short8 a1 = *(const short8*)(hrow + 32);   // k in [32,64)
    __syncthreads();

    // ---- phase B: per-edge scalar classes; prefetch w2 chunk 0 ----
    int4 p0, p1;
    {
        const int4* wsrc = (const int4*)(w2f);
        p0 = wsrc[t]; p1 = wsrc[256 + t];
    }
    {
        int el = t >> 2, part = t & 3;
        float y0 = sh_s[el][0], y1x = sh_s[el][1], y1y = sh_s[el][2], y1z = sh_s[el][3];
        #pragma unroll
        for (int uu = 0; uu < 4; ++uu) {
            int u = part * 4 + uu;
            float xs = nf_s[el][u];
            float v0 = nf_s[el][16 + u * 3 + 0];
            float v1 = nf_s[el][16 + u * 3 + 1];
            float v2 = nf_s[el][16 + u * 3 + 2];
            float dot = v0 * y1x + v1 * y1y + v2 * y1z;
            S[0][u][el] = xs * y0;              // -> Wp0
            S[1][u][el] = xs;                   // -> Wp1
            S[2][u][el] = v0;                   // -> Wp2 (m=0)
            S[3][u][el] = v1;                   // -> Wp2 (m=1)
            S[4][u][el] = v2;                   // -> Wp2 (m=2)
            S[5][u][el] = INV_SQRT3_C * dot;    // -> Wp3
        }
    }
    __syncthreads();
    // ---- phase C: commit chunk 0 to LDS (overwrites nf_s region) ----
    ((int4*)w2s[0])[t] = p0;
    ((int4*)w2s[0])[256 + t] = p1;
    __syncthreads();

    const int wcol = lane & 15;
    const int eS   = wid * 16 + ((lane >> 4) << 2);  // C rows: eS..eS+3 (block-local)

    f32x4 acc0 = {0.f, 0.f, 0.f, 0.f};
    f32x4 tv1  = {0.f, 0.f, 0.f, 0.f};
    f32x4 t2a  = {0.f, 0.f, 0.f, 0.f};
    f32x4 t2b  = {0.f, 0.f, 0.f, 0.f};
    f32x4 t2c  = {0.f, 0.f, 0.f, 0.f};

    for (int u = 0; u < 16; ++u) {
        const int buf = u & 1;
        int4 n0, n1;
        if (u < 15) {   // prefetch next 8 KB chunk (issue early, commit late)
            const int4* wsrc = (const int4*)(w2f + (u + 1) * 4096);
            n0 = wsrc[t]; n1 = wsrc[256 + t];
        }
        f32x4 sA  = *(const f32x4*)&S[0][u][eS];
        f32x4 sX  = *(const f32x4*)&S[1][u][eS];
        f32x4 sV0 = *(const f32x4*)&S[2][u][eS];
        f32x4 sV1 = *(const f32x4*)&S[3][u][eS];
        f32x4 sV2 = *(const f32x4*)&S[4][u][eS];
        f32x4 sB  = *(const f32x4*)&S[5][u][eS];
        #pragma unroll
        for (int k = 0; k < 4; ++k) {
            short8 b0 = *(const short8*)&w2s[buf][(k * 2 + 0) * 512 + lane * 8];
            short8 b1 = *(const short8*)&w2s[buf][(k * 2 + 1) * 512 + lane * 8];
            f32x4 c = {0.f, 0.f, 0.f, 0.f};
            c = __builtin_amdgcn_mfma_f32_16x16x32_bf16(a0, b0, c, 0, 0, 0);
            c = __builtin_amdgcn_mfma_f32_16x16x32_bf16(a1, b1, c, 0, 0, 0);
            float bb = b2_s[k][u][wcol];
            if (k == 0) {
                #pragma unroll
                for (int r = 0; r < 4; ++r) acc0[r] = fmaf(c[r] + bb, sA[r], acc0[r]);
            } else if (k == 1) {
                #pragma unroll
                for (int r = 0; r < 4; ++r) tv1[r] = fmaf(c[r] + bb, sX[r], tv1[r]);
            } else if (k == 2) {
                #pragma unroll
                for (int r = 0; r < 4; ++r) {
                    float wp = c[r] + bb;
                    t2a[r] = fmaf(wp, sV0[r], t2a[r]);
                    t2b[r] = fmaf(wp, sV1[r], t2b[r]);
                    t2c[r] = fmaf(wp, sV2[r], t2c[r]);
                }
            } else {
                #pragma unroll
                for (int r = 0; r < 4; ++r) acc0[r] = fmaf(c[r] + bb, sB[r], acc0[r]);
            }
        }
        if (u < 15) {
            int4* dst = (int4*)w2s[buf ^ 1];
            dst[t] = n0; dst[256 + t] = n1;
        }
        __syncthreads();
    }

    // ---- epilogue: assemble messages, scatter-add ----
    #pragma unroll
    for (int r = 0; r < 4; ++r) {
        int el = eS + r;
        int node = row_s[el];
        float y0 = sh_s[el][0];
        float* dst = out + node * 64;
        atomicAdd(dst + wcol, PW0_C * acc0[r]);
        float tt1 = tv1[r];
        const float c1 = PW1_C * INV_SQRT3_C;
        atomicAdd(dst + 16 + wcol * 3 + 0, c1 * (tt1 * sh_s[el][1] + t2a[r] * y0));
        atomicAdd(dst + 16 + wcol * 3 + 1, c1 * (tt1 * sh_s[el][2] + t2b[r] * y0));
        atomicAdd(dst + 16 + wcol * 3 + 2, c1 * (tt1 * sh_s[el][3] + t2c[r] * y0));
    }
}

extern "C" void kernel_launch(void* const* d_in, const int* in_sizes, int n_in,
                              void* d_out, int out_size, void* d_ws, size_t ws_size,
                              hipStream_t stream) {
    const float* nf   = (const float*)d_in[0];
    const float* ea   = (const float*)d_in[1];
    const float* sh   = (const float*)d_in[2];
    const float* w1   = (const float*)d_in[3];
    const float* b1   = (const float*)d_in[4];
    const float* w2   = (const float*)d_in[5];
    const float* b2   = (const float*)d_in[6];
    const float* wsi0 = (const float*)d_in[7];
    const float* wsi1 = (const float*)d_in[8];
    const int*   ei   = (const int*)d_in[9];
    float* out = (float*)d_out;

    unsigned short* h   = (unsigned short*)d_ws;                  // 200000*64 bf16 = 25.6 MB
    unsigned short* w2f = h + (size_t)N_EDGES_C * 64;             // 65536 bf16 = 128 KB

    k_h  <<<50000, 256, 0, stream>>>(ea, w1, b1, h);
    k_w2 <<<256,   256, 0, stream>>>(w2, w2f);
    k_si <<<5000,  256, 0, stream>>>(nf, wsi0, wsi1, out);
    k_main<<<3125, 256, 0, stream>>>(nf, sh, ei, h, w2f, b2, out);
}